// Round 2
// baseline (1930.378 us; speedup 1.0000x reference)
//
#include <hip/hip_runtime.h>

#define N_NODES 100000
#define N_EDGES 3200000
#define HD      256
#define NGRAPH  128
#define NCLASS  10
#define BN_EPS  1e-5f

typedef unsigned short u16;
typedef __attribute__((ext_vector_type(4))) float f32x4;
typedef __attribute__((ext_vector_type(8))) short bf16x8;
typedef __attribute__((ext_vector_type(8))) u16   u16x8;
typedef __attribute__((ext_vector_type(4))) u16   u16x4;

__device__ __forceinline__ float b2f(u16 u){ return __uint_as_float(((unsigned)u) << 16); }
__device__ __forceinline__ u16 f2b(float f){
  unsigned x = __float_as_uint(f);
  x += 0x7fffu + ((x >> 16) & 1u);
  return (u16)(x >> 16);
}
__device__ __forceinline__ f32x4 c4(u16x4 v){
  f32x4 r = { b2f(v[0]), b2f(v[1]), b2f(v[2]), b2f(v[3]) };
  return r;
}

// ---------------- conversion / preprocessing ----------------

__global__ __launch_bounds__(256) void cvt_k(const float* __restrict__ x, u16* __restrict__ xb){
  size_t i = ((size_t)blockIdx.x * 256 + threadIdx.x) * 8;
  f32x4 v0 = *(const f32x4*)(x + i);
  f32x4 v1 = *(const f32x4*)(x + i + 4);
  u16x8 o = { f2b(v0[0]), f2b(v0[1]), f2b(v0[2]), f2b(v0[3]),
              f2b(v1[0]), f2b(v1[1]), f2b(v1[2]), f2b(v1[3]) };
  *(u16x8*)(xb + i) = o;
}

__global__ __launch_bounds__(256) void wt_k(const float* __restrict__ W, u16* __restrict__ Wt){
  int i = blockIdx.x * 256 + threadIdx.x;      // 65536 elements
  int k = i >> 8, n = i & 255;
  Wt[n * HD + k] = f2b(W[k * HD + n]);         // Wt[col][k]
}

__global__ __launch_bounds__(256) void cnt_k(const int* __restrict__ ei, int* __restrict__ cnt){
  int e = blockIdx.x * 256 + threadIdx.x;
  if (e < N_EDGES) atomicAdd(&cnt[ei[N_EDGES + e]], 1);
}

__global__ __launch_bounds__(256) void scan1_k(const int* __restrict__ cnt, int* __restrict__ tmp,
                                               int* __restrict__ bsum){
  __shared__ int sh[256];
  int tid = threadIdx.x;
  int i = blockIdx.x * 256 + tid;
  int v = (i < N_NODES) ? cnt[i] : 0;
  sh[tid] = v;
  __syncthreads();
  #pragma unroll
  for (int off = 1; off < 256; off <<= 1){
    int t = (tid >= off) ? sh[tid - off] : 0;
    __syncthreads();
    sh[tid] += t;
    __syncthreads();
  }
  if (i < N_NODES) tmp[i] = sh[tid];
  if (tid == 255) bsum[blockIdx.x] = sh[255];
}

__global__ __launch_bounds__(512) void scan2_k(const int* __restrict__ bsum, int* __restrict__ boff, int nb){
  __shared__ int sh[512];
  int tid = threadIdx.x;
  int v = (tid < nb) ? bsum[tid] : 0;
  sh[tid] = v;
  __syncthreads();
  for (int off = 1; off < 512; off <<= 1){
    int t = (tid >= off) ? sh[tid - off] : 0;
    __syncthreads();
    sh[tid] += t;
    __syncthreads();
  }
  if (tid < nb) boff[tid] = sh[tid] - v;   // exclusive
}

__global__ __launch_bounds__(256) void scan3_k(const int* __restrict__ tmp, const int* __restrict__ boff,
                                               int* __restrict__ rowptr){
  int i = blockIdx.x * 256 + threadIdx.x;   // 0..N inclusive
  if (i > N_NODES) return;
  if (i == 0) rowptr[0] = 0;
  else rowptr[i] = tmp[i - 1] + boff[(i - 1) >> 8];
}

__global__ __launch_bounds__(256) void fill_k(const int* __restrict__ ei, const int* __restrict__ rowptr,
                                              int* __restrict__ fill, int* __restrict__ colx){
  int e = blockIdx.x * 256 + threadIdx.x;
  if (e < N_EDGES){
    int d = ei[N_EDGES + e];
    int pos = atomicAdd(&fill[d], 1);
    colx[rowptr[d] + pos] = ei[e];
  }
}

__global__ __launch_bounds__(256) void dis_k(const int* __restrict__ cnt, float* __restrict__ dis){
  int i = blockIdx.x * 256 + threadIdx.x;
  if (i < N_NODES) dis[i] = rsqrtf((float)(cnt[i] + 1));   // in-degree + self-loop
}

// ---------------- GEMM: HN = (X @ W) * dis[row], bf16 in/out ----------------

__device__ __forceinline__ int swzoff(int row, int kel){
  return (row * 512 + kel * 2) ^ ((row & 7) << 4);
}

__global__ __launch_bounds__(256) void gemm_k(const u16* __restrict__ X, const u16* __restrict__ Wt,
                                              const float* __restrict__ dis, u16* __restrict__ HN)
{
  __shared__ u16x8 AsV[2048];   // 32 KB, byte-XOR-swizzled [64][256] bf16
  __shared__ u16x8 BsV[2048];
  char* As = (char*)AsV;
  char* Bs = (char*)BsV;
  int tid = threadIdx.x;
  int colbase = blockIdx.x * 64;   // x fastest => 4 col-panels share one A tile in L2
  int rowbase = blockIdx.y * 64;
  {
    int r = tid >> 2, q = tid & 3;
    int grow = rowbase + r;
    const u16* src = X + (size_t)grow * HD + q * 64;
    #pragma unroll
    for (int j = 0; j < 8; ++j){
      u16x8 v = {0,0,0,0,0,0,0,0};
      if (grow < N_NODES) v = *(const u16x8*)(src + j * 8);
      *(u16x8*)(As + swzoff(r, q * 64 + j * 8)) = v;
    }
    const u16* wsrc = Wt + (size_t)(colbase + r) * HD + q * 64;
    #pragma unroll
    for (int j = 0; j < 8; ++j)
      *(u16x8*)(Bs + swzoff(r, q * 64 + j * 8)) = *(const u16x8*)(wsrc + j * 8);
  }
  __syncthreads();

  int w = tid >> 6, lane = tid & 63;
  int wm = w >> 1, wn = w & 1;
  int lr = lane & 15, lg = lane >> 4;

  f32x4 acc00 = {0,0,0,0}, acc01 = {0,0,0,0}, acc10 = {0,0,0,0}, acc11 = {0,0,0,0};
  #pragma unroll
  for (int ks = 0; ks < 8; ++ks){
    int ka = ks * 32 + lg * 8;
    bf16x8 a0 = *(const bf16x8*)(As + swzoff(wm * 32 + lr,      ka));
    bf16x8 a1 = *(const bf16x8*)(As + swzoff(wm * 32 + 16 + lr, ka));
    bf16x8 b0 = *(const bf16x8*)(Bs + swzoff(wn * 32 + lr,      ka));
    bf16x8 b1 = *(const bf16x8*)(Bs + swzoff(wn * 32 + 16 + lr, ka));
    acc00 = __builtin_amdgcn_mfma_f32_16x16x32_bf16(a0, b0, acc00, 0, 0, 0);
    acc01 = __builtin_amdgcn_mfma_f32_16x16x32_bf16(a0, b1, acc01, 0, 0, 0);
    acc10 = __builtin_amdgcn_mfma_f32_16x16x32_bf16(a1, b0, acc10, 0, 0, 0);
    acc11 = __builtin_amdgcn_mfma_f32_16x16x32_bf16(a1, b1, acc11, 0, 0, 0);
  }

  // C/D layout: col = lane&15, row = (lane>>4)*4 + reg  [measured m89]
  #pragma unroll
  for (int mt = 0; mt < 2; ++mt){
    f32x4 ac0 = mt ? acc10 : acc00;
    f32x4 ac1 = mt ? acc11 : acc01;
    #pragma unroll
    for (int r = 0; r < 4; ++r){
      int grow = rowbase + wm * 32 + mt * 16 + lg * 4 + r;
      if (grow < N_NODES){
        float dd = dis[grow];
        size_t base = (size_t)grow * HD + colbase + wn * 32 + lr;
        HN[base]      = f2b(ac0[r] * dd);
        HN[base + 16] = f2b(ac1[r] * dd);
      }
    }
  }
}

// ---------------- aggregation: OUT[d] = dis[d]*(sum_{edges} HN[s] + HN[d]) ----------------

__global__ __launch_bounds__(256) void agg_k(const u16* __restrict__ HN, const int* __restrict__ rowptr,
                                             const int* __restrict__ colx, const float* __restrict__ dis,
                                             float* __restrict__ OUT)
{
  int w = threadIdx.x >> 6, lane = threadIdx.x & 63;
  int node = blockIdx.x * 4 + w;
  if (node >= N_NODES) return;
  int c0 = lane * 4;
  f32x4 a0 = {0,0,0,0}, a1 = {0,0,0,0};
  int e = rowptr[node], end = rowptr[node + 1];
  for (; e + 2 <= end; e += 2){
    int s0 = colx[e], s1 = colx[e + 1];
    u16x4 v0 = *(const u16x4*)(HN + (size_t)s0 * HD + c0);
    u16x4 v1 = *(const u16x4*)(HN + (size_t)s1 * HD + c0);
    a0 += c4(v0);
    a1 += c4(v1);
  }
  if (e < end){
    int s0 = colx[e];
    a0 += c4(*(const u16x4*)(HN + (size_t)s0 * HD + c0));
  }
  a0 += c4(*(const u16x4*)(HN + (size_t)node * HD + c0));  // self-loop
  f32x4 res = (a0 + a1) * dis[node];
  *(f32x4*)(OUT + (size_t)node * HD + c0) = res;
}

// ---------------- batch-norm over nodes ----------------

__global__ __launch_bounds__(256) void stat_k(const float* __restrict__ OUT, float* __restrict__ sums){
  int c = threadIdx.x;
  float s = 0.f, q = 0.f;
  for (int r = blockIdx.x; r < N_NODES; r += gridDim.x){
    float v = OUT[(size_t)r * HD + c];
    s += v; q += v * v;
  }
  atomicAdd(&sums[c], s);
  atomicAdd(&sums[HD + c], q);
}

__global__ __launch_bounds__(256) void prep_k(const float* __restrict__ sums, const float* __restrict__ gamma,
                                              const float* __restrict__ beta, float* __restrict__ prm){
  int c = threadIdx.x;
  float mean = sums[c] / (float)N_NODES;
  float var  = fmaxf(sums[HD + c] / (float)N_NODES - mean * mean, 0.f);
  float inv  = rsqrtf(var + BN_EPS);
  float a = gamma[c] * inv;
  prm[c] = a;
  prm[HD + c] = beta[c] - mean * a;
}

__global__ __launch_bounds__(256) void norm_k(const float* __restrict__ OUT, const float* __restrict__ prm,
                                              u16* __restrict__ XB){
  size_t i = (size_t)blockIdx.x * 256 + threadIdx.x;   // over N*HD/4
  int cq = (int)(i & 63);
  size_t base = i * 4;
  f32x4 v = *(const f32x4*)(OUT + base);
  f32x4 a = *(const f32x4*)(prm + cq * 4);
  f32x4 b = *(const f32x4*)(prm + HD + cq * 4);
  f32x4 y = v * a + b;
  u16x4 o = { f2b(fmaxf(y[0], 0.f)), f2b(fmaxf(y[1], 0.f)),
              f2b(fmaxf(y[2], 0.f)), f2b(fmaxf(y[3], 0.f)) };
  *(u16x4*)(XB + base) = o;
}

// ---------------- pooling + MLP head ----------------

__global__ __launch_bounds__(256) void bnd_k(const int* __restrict__ batch, int* __restrict__ gs,
                                             int* __restrict__ ge){
  int i = blockIdx.x * 256 + threadIdx.x;
  if (i < N_NODES){
    int g = batch[i];
    atomicMin(&gs[g], i);
    atomicMax(&ge[g], i + 1);
  }
}

__global__ __launch_bounds__(256) void pool_k(const u16* __restrict__ xb, const int* __restrict__ gs,
                                              const int* __restrict__ ge, float* __restrict__ pooled){
  __shared__ float red[4][HD];
  int g = blockIdx.x;
  int s = gs[g], e = ge[g];
  int w = threadIdx.x >> 6;
  int c0 = (threadIdx.x & 63) * 4;
  f32x4 acc = {0,0,0,0};
  for (int r = s + w; r < e; r += 4){
    u16x4 v = *(const u16x4*)(xb + (size_t)r * HD + c0);
    acc += c4(v);
  }
  *(f32x4*)&red[w][c0] = acc;
  __syncthreads();
  if (w == 0){
    f32x4 t = *(f32x4*)&red[0][c0];
    t += *(f32x4*)&red[1][c0];
    t += *(f32x4*)&red[2][c0];
    t += *(f32x4*)&red[3][c0];
    float cntf = (e > s) ? (float)(e - s) : 1.0f;
    *(f32x4*)(pooled + g * HD + c0) = t * (1.0f / cntf);
  }
}

__global__ __launch_bounds__(256) void lin1_k(const float* __restrict__ pooled, const float* __restrict__ w,
                                              const float* __restrict__ b, float* __restrict__ z1){
  __shared__ float pr[HD];
  int g = blockIdx.x, c = threadIdx.x;
  pr[c] = pooled[g * HD + c];
  __syncthreads();
  float acc = b[c];
  #pragma unroll 8
  for (int k = 0; k < HD; ++k) acc = fmaf(pr[k], w[k * HD + c], acc);
  z1[g * HD + c] = acc;
}

__global__ __launch_bounds__(256) void bn1_k(float* __restrict__ z1, const float* __restrict__ g,
                                             const float* __restrict__ b){
  int c = threadIdx.x;
  float s = 0.f, q = 0.f;
  for (int r = 0; r < NGRAPH; ++r){
    float v = z1[r * HD + c];
    s += v; q += v * v;
  }
  float mean = s / (float)NGRAPH;
  float var  = fmaxf(q / (float)NGRAPH - mean * mean, 0.f);
  float inv  = rsqrtf(var + BN_EPS);
  float a = g[c] * inv, sh = b[c] - mean * a;
  for (int r = 0; r < NGRAPH; ++r)
    z1[r * HD + c] = fmaxf(z1[r * HD + c] * a + sh, 0.f);
}

__global__ __launch_bounds__(256) void lin2_k(const float* __restrict__ z1, const float* __restrict__ w,
                                              const float* __restrict__ b, float* __restrict__ out){
  __shared__ float zr[HD];
  int g = blockIdx.x;
  zr[threadIdx.x] = z1[g * HD + threadIdx.x];
  __syncthreads();
  if (threadIdx.x < NCLASS){
    float acc = b[threadIdx.x];
    #pragma unroll 8
    for (int k = 0; k < HD; ++k) acc = fmaf(zr[k], w[k * NCLASS + threadIdx.x], acc);
    out[g * NCLASS + threadIdx.x] = acc;
  }
}

// ---------------- host launch ----------------

extern "C" void kernel_launch(void* const* d_in, const int* in_sizes, int n_in,
                              void* d_out, int out_size, void* d_ws, size_t ws_size,
                              hipStream_t stream)
{
  const float* x      = (const float*)d_in[0];
  const int*   ei     = (const int*)d_in[1];
  const int*   batch  = (const int*)d_in[2];
  const float* W[3]   = {(const float*)d_in[3], (const float*)d_in[7], (const float*)d_in[11]};
  const float* gam[3] = {(const float*)d_in[5], (const float*)d_in[9], (const float*)d_in[13]};
  const float* bet[3] = {(const float*)d_in[6], (const float*)d_in[10], (const float*)d_in[14]};
  const float* lin1_w = (const float*)d_in[15];
  const float* lin1_b = (const float*)d_in[16];
  const float* bn1_g  = (const float*)d_in[17];
  const float* bn1_b  = (const float*)d_in[18];
  const float* lin2_w = (const float*)d_in[19];
  const float* lin2_b = (const float*)d_in[20];
  float* out = (float*)d_out;

  char* ws = (char*)d_ws;
  size_t off = 0;
  auto alloc = [&](size_t bytes) -> void* {
    void* p = ws + off;
    off = (off + bytes + 255) & ~(size_t)255;
    return p;
  };
  u16*   xb     = (u16*)alloc((size_t)N_NODES * HD * 2);
  u16*   hn     = (u16*)alloc((size_t)N_NODES * HD * 2);
  float* outf   = (float*)alloc((size_t)N_NODES * HD * 4);
  u16*   wt     = (u16*)alloc((size_t)3 * HD * HD * 2);
  int*   cnt    = (int*)alloc((size_t)N_NODES * 4);
  int*   fill   = (int*)alloc((size_t)N_NODES * 4);
  int*   rowptr = (int*)alloc((size_t)(N_NODES + 1) * 4);
  int*   tmp    = (int*)alloc((size_t)N_NODES * 4);
  int*   bsum   = (int*)alloc(512 * 4);
  int*   boff   = (int*)alloc(512 * 4);
  int*   colx   = (int*)alloc((size_t)N_EDGES * 4);
  float* dis    = (float*)alloc((size_t)N_NODES * 4);
  float* bnsum  = (float*)alloc(2 * HD * 4);
  float* prm    = (float*)alloc(2 * HD * 4);
  int*   gs     = (int*)alloc(NGRAPH * 4);
  int*   ge     = (int*)alloc(NGRAPH * 4);
  float* pooled = (float*)alloc((size_t)NGRAPH * HD * 4);
  float* z1     = (float*)alloc((size_t)NGRAPH * HD * 4);
  (void)ws_size; (void)n_in; (void)in_sizes; (void)out_size;

  const int NB1 = (N_NODES + 255) / 256;            // 391

  hipMemsetAsync(cnt, 0, (size_t)N_NODES * 4, stream);
  hipMemsetAsync(fill, 0, (size_t)N_NODES * 4, stream);

  cvt_k<<<12500, 256, 0, stream>>>(x, xb);
  for (int l = 0; l < 3; ++l)
    wt_k<<<256, 256, 0, stream>>>(W[l], wt + (size_t)l * HD * HD);

  cnt_k<<<12500, 256, 0, stream>>>(ei, cnt);
  scan1_k<<<NB1, 256, 0, stream>>>(cnt, tmp, bsum);
  scan2_k<<<1, 512, 0, stream>>>(bsum, boff, NB1);
  scan3_k<<<(N_NODES + 256) / 256 + 1, 256, 0, stream>>>(tmp, boff, rowptr);
  fill_k<<<12500, 256, 0, stream>>>(ei, rowptr, fill, colx);
  dis_k<<<NB1, 256, 0, stream>>>(cnt, dis);

  for (int l = 0; l < 3; ++l){
    gemm_k<<<dim3(4, 1563), 256, 0, stream>>>(xb, wt + (size_t)l * HD * HD, dis, hn);
    agg_k<<<25000, 256, 0, stream>>>(hn, rowptr, colx, dis, outf);
    hipMemsetAsync(bnsum, 0, 2 * HD * 4, stream);
    stat_k<<<1024, 256, 0, stream>>>(outf, bnsum);
    prep_k<<<1, 256, 0, stream>>>(bnsum, gam[l], bet[l], prm);
    norm_k<<<25000, 256, 0, stream>>>(outf, prm, xb);
  }

  hipMemsetAsync(gs, 0x7f, NGRAPH * 4, stream);
  hipMemsetAsync(ge, 0, NGRAPH * 4, stream);
  bnd_k<<<NB1, 256, 0, stream>>>(batch, gs, ge);
  pool_k<<<NGRAPH, 256, 0, stream>>>(xb, gs, ge, pooled);
  lin1_k<<<NGRAPH, 256, 0, stream>>>(pooled, lin1_w, lin1_b, z1);
  bn1_k<<<1, 256, 0, stream>>>(z1, bn1_g, bn1_b);
  lin2_k<<<NGRAPH, 256, 0, stream>>>(z1, lin2_w, lin2_b, out);
}

// Round 3
// 1575.418 us; speedup vs baseline: 1.2253x; 1.2253x over previous
//
#include <hip/hip_runtime.h>

#define N_NODES 100000
#define N_EDGES 3200000
#define HD      256
#define NGRAPH  128
#define NCLASS  10
#define BN_EPS  1e-5f

typedef unsigned short u16;
typedef __attribute__((ext_vector_type(4))) float f32x4;
typedef __attribute__((ext_vector_type(8))) short bf16x8;
typedef __attribute__((ext_vector_type(8))) u16   u16x8;
typedef __attribute__((ext_vector_type(4))) u16   u16x4;

__device__ __forceinline__ float b2f(u16 u){ return __uint_as_float(((unsigned)u) << 16); }
__device__ __forceinline__ u16 f2b(float f){
  unsigned x = __float_as_uint(f);
  x += 0x7fffu + ((x >> 16) & 1u);
  return (u16)(x >> 16);
}
__device__ __forceinline__ f32x4 c4(u16x4 v){
  f32x4 r = { b2f(v[0]), b2f(v[1]), b2f(v[2]), b2f(v[3]) };
  return r;
}

// ---------------- conversion / preprocessing ----------------

__global__ __launch_bounds__(256) void cvt_k(const float* __restrict__ x, u16* __restrict__ xb){
  size_t i = ((size_t)blockIdx.x * 256 + threadIdx.x) * 8;
  f32x4 v0 = *(const f32x4*)(x + i);
  f32x4 v1 = *(const f32x4*)(x + i + 4);
  u16x8 o = { f2b(v0[0]), f2b(v0[1]), f2b(v0[2]), f2b(v0[3]),
              f2b(v1[0]), f2b(v1[1]), f2b(v1[2]), f2b(v1[3]) };
  *(u16x8*)(xb + i) = o;
}

__global__ __launch_bounds__(256) void wt_k(const float* __restrict__ W, u16* __restrict__ Wt){
  int i = blockIdx.x * 256 + threadIdx.x;      // 65536 elements
  int k = i >> 8, n = i & 255;
  Wt[n * HD + k] = f2b(W[k * HD + n]);         // Wt[col][k]
}

__global__ __launch_bounds__(256) void cnt_k(const int* __restrict__ ei, int* __restrict__ cnt){
  int e = blockIdx.x * 256 + threadIdx.x;
  if (e < N_EDGES) atomicAdd(&cnt[ei[N_EDGES + e]], 1);
}

__global__ __launch_bounds__(256) void scan1_k(const int* __restrict__ cnt, int* __restrict__ tmp,
                                               int* __restrict__ bsum){
  __shared__ int sh[256];
  int tid = threadIdx.x;
  int i = blockIdx.x * 256 + tid;
  int v = (i < N_NODES) ? cnt[i] : 0;
  sh[tid] = v;
  __syncthreads();
  #pragma unroll
  for (int off = 1; off < 256; off <<= 1){
    int t = (tid >= off) ? sh[tid - off] : 0;
    __syncthreads();
    sh[tid] += t;
    __syncthreads();
  }
  if (i < N_NODES) tmp[i] = sh[tid];
  if (tid == 255) bsum[blockIdx.x] = sh[255];
}

__global__ __launch_bounds__(512) void scan2_k(const int* __restrict__ bsum, int* __restrict__ boff, int nb){
  __shared__ int sh[512];
  int tid = threadIdx.x;
  int v = (tid < nb) ? bsum[tid] : 0;
  sh[tid] = v;
  __syncthreads();
  for (int off = 1; off < 512; off <<= 1){
    int t = (tid >= off) ? sh[tid - off] : 0;
    __syncthreads();
    sh[tid] += t;
    __syncthreads();
  }
  if (tid < nb) boff[tid] = sh[tid] - v;   // exclusive
}

__global__ __launch_bounds__(256) void scan3_k(const int* __restrict__ tmp, const int* __restrict__ boff,
                                               int* __restrict__ rowptr){
  int i = blockIdx.x * 256 + threadIdx.x;   // 0..N inclusive
  if (i > N_NODES) return;
  if (i == 0) rowptr[0] = 0;
  else rowptr[i] = tmp[i - 1] + boff[(i - 1) >> 8];
}

__global__ __launch_bounds__(256) void fill_k(const int* __restrict__ ei, const int* __restrict__ rowptr,
                                              int* __restrict__ fill, int* __restrict__ colx){
  int e = blockIdx.x * 256 + threadIdx.x;
  if (e < N_EDGES){
    int d = ei[N_EDGES + e];
    int pos = atomicAdd(&fill[d], 1);
    colx[rowptr[d] + pos] = ei[e];
  }
}

__global__ __launch_bounds__(256) void dis_k(const int* __restrict__ cnt, float* __restrict__ dis){
  int i = blockIdx.x * 256 + threadIdx.x;
  if (i < N_NODES) dis[i] = rsqrtf((float)(cnt[i] + 1));   // in-degree + self-loop
}

// ---------------- GEMM: HN = (X @ W) * dis[row], bf16 in/out ----------------

__device__ __forceinline__ int swzoff(int row, int kel){
  return (row * 512 + kel * 2) ^ ((row & 7) << 4);
}

__global__ __launch_bounds__(256) void gemm_k(const u16* __restrict__ X, const u16* __restrict__ Wt,
                                              const float* __restrict__ dis, u16* __restrict__ HN)
{
  __shared__ u16x8 AsV[2048];   // 32 KB, byte-XOR-swizzled [64][256] bf16
  __shared__ u16x8 BsV[2048];
  char* As = (char*)AsV;
  char* Bs = (char*)BsV;
  int tid = threadIdx.x;
  int colbase = blockIdx.x * 64;   // x fastest => 4 col-panels share one A tile in L2
  int rowbase = blockIdx.y * 64;
  {
    int r = tid >> 2, q = tid & 3;
    int grow = rowbase + r;
    const u16* src = X + (size_t)grow * HD + q * 64;
    #pragma unroll
    for (int j = 0; j < 8; ++j){
      u16x8 v = {0,0,0,0,0,0,0,0};
      if (grow < N_NODES) v = *(const u16x8*)(src + j * 8);
      *(u16x8*)(As + swzoff(r, q * 64 + j * 8)) = v;
    }
    const u16* wsrc = Wt + (size_t)(colbase + r) * HD + q * 64;
    #pragma unroll
    for (int j = 0; j < 8; ++j)
      *(u16x8*)(Bs + swzoff(r, q * 64 + j * 8)) = *(const u16x8*)(wsrc + j * 8);
  }
  __syncthreads();

  int w = tid >> 6, lane = tid & 63;
  int wm = w >> 1, wn = w & 1;
  int lr = lane & 15, lg = lane >> 4;

  f32x4 acc00 = {0,0,0,0}, acc01 = {0,0,0,0}, acc10 = {0,0,0,0}, acc11 = {0,0,0,0};
  #pragma unroll
  for (int ks = 0; ks < 8; ++ks){
    int ka = ks * 32 + lg * 8;
    bf16x8 a0 = *(const bf16x8*)(As + swzoff(wm * 32 + lr,      ka));
    bf16x8 a1 = *(const bf16x8*)(As + swzoff(wm * 32 + 16 + lr, ka));
    bf16x8 b0 = *(const bf16x8*)(Bs + swzoff(wn * 32 + lr,      ka));
    bf16x8 b1 = *(const bf16x8*)(Bs + swzoff(wn * 32 + 16 + lr, ka));
    acc00 = __builtin_amdgcn_mfma_f32_16x16x32_bf16(a0, b0, acc00, 0, 0, 0);
    acc01 = __builtin_amdgcn_mfma_f32_16x16x32_bf16(a0, b1, acc01, 0, 0, 0);
    acc10 = __builtin_amdgcn_mfma_f32_16x16x32_bf16(a1, b0, acc10, 0, 0, 0);
    acc11 = __builtin_amdgcn_mfma_f32_16x16x32_bf16(a1, b1, acc11, 0, 0, 0);
  }

  // C/D layout: col = lane&15, row = (lane>>4)*4 + reg  [measured m89]
  #pragma unroll
  for (int mt = 0; mt < 2; ++mt){
    f32x4 ac0 = mt ? acc10 : acc00;
    f32x4 ac1 = mt ? acc11 : acc01;
    #pragma unroll
    for (int r = 0; r < 4; ++r){
      int grow = rowbase + wm * 32 + mt * 16 + lg * 4 + r;
      if (grow < N_NODES){
        float dd = dis[grow];
        size_t base = (size_t)grow * HD + colbase + wn * 32 + lr;
        HN[base]      = f2b(ac0[r] * dd);
        HN[base + 16] = f2b(ac1[r] * dd);
      }
    }
  }
}

// ---------------- aggregation: OUTB[d] = bf16( dis[d]*(sum_{edges} HN[s] + HN[d]) ) ----------------

__global__ __launch_bounds__(256) void agg_k(const u16* __restrict__ HN, const int* __restrict__ rowptr,
                                             const int* __restrict__ colx, const float* __restrict__ dis,
                                             u16* __restrict__ OUTB)
{
  int w = threadIdx.x >> 6, lane = threadIdx.x & 63;
  int node = blockIdx.x * 4 + w;
  if (node >= N_NODES) return;
  int c0 = lane * 4;
  f32x4 a0 = {0,0,0,0}, a1 = {0,0,0,0};
  int e = rowptr[node], end = rowptr[node + 1];
  for (; e + 2 <= end; e += 2){
    int s0 = colx[e], s1 = colx[e + 1];
    u16x4 v0 = *(const u16x4*)(HN + (size_t)s0 * HD + c0);
    u16x4 v1 = *(const u16x4*)(HN + (size_t)s1 * HD + c0);
    a0 += c4(v0);
    a1 += c4(v1);
  }
  if (e < end){
    int s0 = colx[e];
    a0 += c4(*(const u16x4*)(HN + (size_t)s0 * HD + c0));
  }
  a0 += c4(*(const u16x4*)(HN + (size_t)node * HD + c0));  // self-loop
  f32x4 res = (a0 + a1) * dis[node];
  u16x4 o = { f2b(res[0]), f2b(res[1]), f2b(res[2]), f2b(res[3]) };
  *(u16x4*)(OUTB + (size_t)node * HD + c0) = o;
}

// ---------------- batch-norm over nodes ----------------

__global__ __launch_bounds__(256) void stat_k(const u16* __restrict__ OUTB, float* __restrict__ sums){
  int c = threadIdx.x;
  float s = 0.f, q = 0.f;
  for (int r = blockIdx.x; r < N_NODES; r += gridDim.x){
    float v = b2f(OUTB[(size_t)r * HD + c]);
    s += v; q += v * v;
  }
  atomicAdd(&sums[c], s);
  atomicAdd(&sums[HD + c], q);
}

__global__ __launch_bounds__(256) void prep_k(const float* __restrict__ sums, const float* __restrict__ gamma,
                                              const float* __restrict__ beta, float* __restrict__ prm){
  int c = threadIdx.x;
  float mean = sums[c] / (float)N_NODES;
  float var  = fmaxf(sums[HD + c] / (float)N_NODES - mean * mean, 0.f);
  float inv  = rsqrtf(var + BN_EPS);
  float a = gamma[c] * inv;
  prm[c] = a;
  prm[HD + c] = beta[c] - mean * a;
}

__global__ __launch_bounds__(256) void norm_k(const u16* __restrict__ OUTB, const float* __restrict__ prm,
                                              u16* __restrict__ XB){
  size_t i = (size_t)blockIdx.x * 256 + threadIdx.x;   // over N*HD/4
  int cq = (int)(i & 63);
  size_t base = i * 4;
  f32x4 v = c4(*(const u16x4*)(OUTB + base));
  f32x4 a = *(const f32x4*)(prm + cq * 4);
  f32x4 b = *(const f32x4*)(prm + HD + cq * 4);
  f32x4 y = v * a + b;
  u16x4 o = { f2b(fmaxf(y[0], 0.f)), f2b(fmaxf(y[1], 0.f)),
              f2b(fmaxf(y[2], 0.f)), f2b(fmaxf(y[3], 0.f)) };
  *(u16x4*)(XB + base) = o;
}

// ---------------- pooling + MLP head ----------------

// batch is SORTED: boundary-scan instead of 200k contended atomics.
__global__ __launch_bounds__(256) void bnd2_k(const int* __restrict__ batch, int* __restrict__ gs,
                                              int* __restrict__ ge){
  int i = blockIdx.x * 256 + threadIdx.x;
  if (i >= N_NODES) return;
  int b = batch[i];
  if (i == 0) gs[b] = 0;
  else {
    int p = batch[i - 1];
    if (p != b){ ge[p] = i; gs[b] = i; }
  }
  if (i == N_NODES - 1) ge[b] = N_NODES;
}

__global__ __launch_bounds__(256) void pool_k(const u16* __restrict__ xb, const int* __restrict__ gs,
                                              const int* __restrict__ ge, float* __restrict__ pooled){
  __shared__ float red[4][HD];
  int g = blockIdx.x;
  int s = gs[g], e = ge[g];
  int w = threadIdx.x >> 6;
  int c0 = (threadIdx.x & 63) * 4;
  f32x4 acc = {0,0,0,0};
  for (int r = s + w; r < e; r += 4){
    u16x4 v = *(const u16x4*)(xb + (size_t)r * HD + c0);
    acc += c4(v);
  }
  *(f32x4*)&red[w][c0] = acc;
  __syncthreads();
  if (w == 0){
    f32x4 t = *(f32x4*)&red[0][c0];
    t += *(f32x4*)&red[1][c0];
    t += *(f32x4*)&red[2][c0];
    t += *(f32x4*)&red[3][c0];
    float cntf = (e > s) ? (float)(e - s) : 1.0f;
    *(f32x4*)(pooled + g * HD + c0) = t * (1.0f / cntf);
  }
}

__global__ __launch_bounds__(256) void lin1_k(const float* __restrict__ pooled, const float* __restrict__ w,
                                              const float* __restrict__ b, float* __restrict__ z1){
  __shared__ float pr[HD];
  int g = blockIdx.x, c = threadIdx.x;
  pr[c] = pooled[g * HD + c];
  __syncthreads();
  float acc = b[c];
  #pragma unroll 8
  for (int k = 0; k < HD; ++k) acc = fmaf(pr[k], w[k * HD + c], acc);
  z1[g * HD + c] = acc;
}

__global__ __launch_bounds__(256) void bn1_k(float* __restrict__ z1, const float* __restrict__ g,
                                             const float* __restrict__ b){
  int c = threadIdx.x;
  float s = 0.f, q = 0.f;
  for (int r = 0; r < NGRAPH; ++r){
    float v = z1[r * HD + c];
    s += v; q += v * v;
  }
  float mean = s / (float)NGRAPH;
  float var  = fmaxf(q / (float)NGRAPH - mean * mean, 0.f);
  float inv  = rsqrtf(var + BN_EPS);
  float a = g[c] * inv, sh = b[c] - mean * a;
  for (int r = 0; r < NGRAPH; ++r)
    z1[r * HD + c] = fmaxf(z1[r * HD + c] * a + sh, 0.f);
}

__global__ __launch_bounds__(256) void lin2_k(const float* __restrict__ z1, const float* __restrict__ w,
                                              const float* __restrict__ b, float* __restrict__ out){
  __shared__ float zr[HD];
  int g = blockIdx.x;
  zr[threadIdx.x] = z1[g * HD + threadIdx.x];
  __syncthreads();
  if (threadIdx.x < NCLASS){
    float acc = b[threadIdx.x];
    #pragma unroll 8
    for (int k = 0; k < HD; ++k) acc = fmaf(zr[k], w[k * NCLASS + threadIdx.x], acc);
    out[g * NCLASS + threadIdx.x] = acc;
  }
}

// ---------------- host launch ----------------

extern "C" void kernel_launch(void* const* d_in, const int* in_sizes, int n_in,
                              void* d_out, int out_size, void* d_ws, size_t ws_size,
                              hipStream_t stream)
{
  const float* x      = (const float*)d_in[0];
  const int*   ei     = (const int*)d_in[1];
  const int*   batch  = (const int*)d_in[2];
  const float* W[3]   = {(const float*)d_in[3], (const float*)d_in[7], (const float*)d_in[11]};
  const float* gam[3] = {(const float*)d_in[5], (const float*)d_in[9], (const float*)d_in[13]};
  const float* bet[3] = {(const float*)d_in[6], (const float*)d_in[10], (const float*)d_in[14]};
  const float* lin1_w = (const float*)d_in[15];
  const float* lin1_b = (const float*)d_in[16];
  const float* bn1_g  = (const float*)d_in[17];
  const float* bn1_b  = (const float*)d_in[18];
  const float* lin2_w = (const float*)d_in[19];
  const float* lin2_b = (const float*)d_in[20];
  float* out = (float*)d_out;

  char* ws = (char*)d_ws;
  size_t off = 0;
  auto alloc = [&](size_t bytes) -> void* {
    void* p = ws + off;
    off = (off + bytes + 255) & ~(size_t)255;
    return p;
  };
  u16*   xb     = (u16*)alloc((size_t)N_NODES * HD * 2);
  u16*   hn     = (u16*)alloc((size_t)N_NODES * HD * 2);
  u16*   outb   = (u16*)alloc((size_t)N_NODES * HD * 2);
  u16*   wt     = (u16*)alloc((size_t)3 * HD * HD * 2);
  int*   cnt    = (int*)alloc((size_t)N_NODES * 4);
  int*   fill   = (int*)alloc((size_t)N_NODES * 4);
  int*   rowptr = (int*)alloc((size_t)(N_NODES + 1) * 4);
  int*   tmp    = (int*)alloc((size_t)N_NODES * 4);
  int*   bsum   = (int*)alloc(512 * 4);
  int*   boff   = (int*)alloc(512 * 4);
  int*   colx   = (int*)alloc((size_t)N_EDGES * 4);
  float* dis    = (float*)alloc((size_t)N_NODES * 4);
  float* bnsum  = (float*)alloc(2 * HD * 4);
  float* prm    = (float*)alloc(2 * HD * 4);
  int*   gs     = (int*)alloc(NGRAPH * 4);
  int*   ge     = (int*)alloc(NGRAPH * 4);
  float* pooled = (float*)alloc((size_t)NGRAPH * HD * 4);
  float* z1     = (float*)alloc((size_t)NGRAPH * HD * 4);
  (void)ws_size; (void)n_in; (void)in_sizes; (void)out_size;

  const int NB1 = (N_NODES + 255) / 256;            // 391

  hipMemsetAsync(cnt, 0, (size_t)N_NODES * 4, stream);
  hipMemsetAsync(fill, 0, (size_t)N_NODES * 4, stream);

  cvt_k<<<12500, 256, 0, stream>>>(x, xb);
  for (int l = 0; l < 3; ++l)
    wt_k<<<256, 256, 0, stream>>>(W[l], wt + (size_t)l * HD * HD);

  cnt_k<<<12500, 256, 0, stream>>>(ei, cnt);
  scan1_k<<<NB1, 256, 0, stream>>>(cnt, tmp, bsum);
  scan2_k<<<1, 512, 0, stream>>>(bsum, boff, NB1);
  scan3_k<<<(N_NODES + 256) / 256 + 1, 256, 0, stream>>>(tmp, boff, rowptr);
  fill_k<<<12500, 256, 0, stream>>>(ei, rowptr, fill, colx);
  dis_k<<<NB1, 256, 0, stream>>>(cnt, dis);

  for (int l = 0; l < 3; ++l){
    gemm_k<<<dim3(4, 1563), 256, 0, stream>>>(xb, wt + (size_t)l * HD * HD, dis, hn);
    agg_k<<<25000, 256, 0, stream>>>(hn, rowptr, colx, dis, outb);
    hipMemsetAsync(bnsum, 0, 2 * HD * 4, stream);
    stat_k<<<1024, 256, 0, stream>>>(outb, bnsum);
    prep_k<<<1, 256, 0, stream>>>(bnsum, gam[l], bet[l], prm);
    norm_k<<<25000, 256, 0, stream>>>(outb, prm, xb);
  }

  hipMemsetAsync(gs, 0x7f, NGRAPH * 4, stream);
  hipMemsetAsync(ge, 0, NGRAPH * 4, stream);
  bnd2_k<<<NB1, 256, 0, stream>>>(batch, gs, ge);
  pool_k<<<NGRAPH, 256, 0, stream>>>(xb, gs, ge, pooled);
  lin1_k<<<NGRAPH, 256, 0, stream>>>(pooled, lin1_w, lin1_b, z1);
  bn1_k<<<1, 256, 0, stream>>>(z1, bn1_g, bn1_b);
  lin2_k<<<NGRAPH, 256, 0, stream>>>(z1, lin2_w, lin2_b, out);
}

// Round 4
// 1567.923 us; speedup vs baseline: 1.2312x; 1.0048x over previous
//
#include <hip/hip_runtime.h>

#define N_NODES 100000
#define N_EDGES 3200000
#define HD      256
#define NGRAPH  128
#define NCLASS  10
#define BN_EPS  1e-5f

typedef unsigned short u16;
typedef __attribute__((ext_vector_type(4))) float f32x4;
typedef __attribute__((ext_vector_type(8))) float f32x8;
typedef __attribute__((ext_vector_type(8))) short bf16x8;
typedef __attribute__((ext_vector_type(8))) u16   u16x8;
typedef __attribute__((ext_vector_type(4))) u16   u16x4;

__device__ __forceinline__ float b2f(u16 u){ return __uint_as_float(((unsigned)u) << 16); }
__device__ __forceinline__ u16 f2b(float f){
  unsigned x = __float_as_uint(f);
  x += 0x7fffu + ((x >> 16) & 1u);
  return (u16)(x >> 16);
}
__device__ __forceinline__ f32x4 c4(u16x4 v){
  f32x4 r = { b2f(v[0]), b2f(v[1]), b2f(v[2]), b2f(v[3]) };
  return r;
}
__device__ __forceinline__ f32x8 c8(u16x8 v){
  f32x8 r = { b2f(v[0]), b2f(v[1]), b2f(v[2]), b2f(v[3]),
              b2f(v[4]), b2f(v[5]), b2f(v[6]), b2f(v[7]) };
  return r;
}

// ---------------- conversion / preprocessing ----------------

__global__ __launch_bounds__(256) void cvt_k(const float* __restrict__ x, u16* __restrict__ xb){
  size_t i = ((size_t)blockIdx.x * 256 + threadIdx.x) * 8;
  f32x4 v0 = *(const f32x4*)(x + i);
  f32x4 v1 = *(const f32x4*)(x + i + 4);
  u16x8 o = { f2b(v0[0]), f2b(v0[1]), f2b(v0[2]), f2b(v0[3]),
              f2b(v1[0]), f2b(v1[1]), f2b(v1[2]), f2b(v1[3]) };
  *(u16x8*)(xb + i) = o;
}

__global__ __launch_bounds__(256) void wt_k(const float* __restrict__ W, u16* __restrict__ Wt){
  int i = blockIdx.x * 256 + threadIdx.x;      // 65536 elements
  int k = i >> 8, n = i & 255;
  Wt[n * HD + k] = f2b(W[k * HD + n]);         // Wt[col][k]
}

__global__ __launch_bounds__(256) void cnt_k(const int* __restrict__ ei, int* __restrict__ cnt){
  int e = blockIdx.x * 256 + threadIdx.x;
  if (e < N_EDGES) atomicAdd(&cnt[ei[N_EDGES + e]], 1);
}

__global__ __launch_bounds__(256) void scan1_k(const int* __restrict__ cnt, int* __restrict__ tmp,
                                               int* __restrict__ bsum){
  __shared__ int sh[256];
  int tid = threadIdx.x;
  int i = blockIdx.x * 256 + tid;
  int v = (i < N_NODES) ? cnt[i] : 0;
  sh[tid] = v;
  __syncthreads();
  #pragma unroll
  for (int off = 1; off < 256; off <<= 1){
    int t = (tid >= off) ? sh[tid - off] : 0;
    __syncthreads();
    sh[tid] += t;
    __syncthreads();
  }
  if (i < N_NODES) tmp[i] = sh[tid];
  if (tid == 255) bsum[blockIdx.x] = sh[255];
}

__global__ __launch_bounds__(512) void scan2_k(const int* __restrict__ bsum, int* __restrict__ boff, int nb){
  __shared__ int sh[512];
  int tid = threadIdx.x;
  int v = (tid < nb) ? bsum[tid] : 0;
  sh[tid] = v;
  __syncthreads();
  for (int off = 1; off < 512; off <<= 1){
    int t = (tid >= off) ? sh[tid - off] : 0;
    __syncthreads();
    sh[tid] += t;
    __syncthreads();
  }
  if (tid < nb) boff[tid] = sh[tid] - v;   // exclusive
}

__global__ __launch_bounds__(256) void scan3_k(const int* __restrict__ tmp, const int* __restrict__ boff,
                                               int* __restrict__ rowptr){
  int i = blockIdx.x * 256 + threadIdx.x;   // 0..N inclusive
  if (i > N_NODES) return;
  if (i == 0) rowptr[0] = 0;
  else rowptr[i] = tmp[i - 1] + boff[(i - 1) >> 8];
}

__global__ __launch_bounds__(256) void fill_k(const int* __restrict__ ei, const int* __restrict__ rowptr,
                                              int* __restrict__ fill, int* __restrict__ colx){
  int e = blockIdx.x * 256 + threadIdx.x;
  if (e < N_EDGES){
    int d = ei[N_EDGES + e];
    int pos = atomicAdd(&fill[d], 1);
    colx[rowptr[d] + pos] = ei[e];
  }
}

__global__ __launch_bounds__(256) void dis_k(const int* __restrict__ cnt, float* __restrict__ dis){
  int i = blockIdx.x * 256 + threadIdx.x;
  if (i < N_NODES) dis[i] = rsqrtf((float)(cnt[i] + 1));   // in-degree + self-loop
}

// ---------------- GEMM: HN = (X @ W) * dis[row], bf16 in/out ----------------

__device__ __forceinline__ int swzoff(int row, int kel){
  return (row * 512 + kel * 2) ^ ((row & 7) << 4);
}

__global__ __launch_bounds__(256) void gemm_k(const u16* __restrict__ X, const u16* __restrict__ Wt,
                                              const float* __restrict__ dis, u16* __restrict__ HN)
{
  __shared__ u16x8 AsV[2048];   // 32 KB, byte-XOR-swizzled [64][256] bf16
  __shared__ u16x8 BsV[2048];
  char* As = (char*)AsV;
  char* Bs = (char*)BsV;
  int tid = threadIdx.x;
  int colbase = blockIdx.x * 64;   // x fastest => 4 col-panels share one A tile in L2
  int rowbase = blockIdx.y * 64;
  {
    int r = tid >> 2, q = tid & 3;
    int grow = rowbase + r;
    const u16* src = X + (size_t)grow * HD + q * 64;
    #pragma unroll
    for (int j = 0; j < 8; ++j){
      u16x8 v = {0,0,0,0,0,0,0,0};
      if (grow < N_NODES) v = *(const u16x8*)(src + j * 8);
      *(u16x8*)(As + swzoff(r, q * 64 + j * 8)) = v;
    }
    const u16* wsrc = Wt + (size_t)(colbase + r) * HD + q * 64;
    #pragma unroll
    for (int j = 0; j < 8; ++j)
      *(u16x8*)(Bs + swzoff(r, q * 64 + j * 8)) = *(const u16x8*)(wsrc + j * 8);
  }
  __syncthreads();

  int w = tid >> 6, lane = tid & 63;
  int wm = w >> 1, wn = w & 1;
  int lr = lane & 15, lg = lane >> 4;

  f32x4 acc00 = {0,0,0,0}, acc01 = {0,0,0,0}, acc10 = {0,0,0,0}, acc11 = {0,0,0,0};
  #pragma unroll
  for (int ks = 0; ks < 8; ++ks){
    int ka = ks * 32 + lg * 8;
    bf16x8 a0 = *(const bf16x8*)(As + swzoff(wm * 32 + lr,      ka));
    bf16x8 a1 = *(const bf16x8*)(As + swzoff(wm * 32 + 16 + lr, ka));
    bf16x8 b0 = *(const bf16x8*)(Bs + swzoff(wn * 32 + lr,      ka));
    bf16x8 b1 = *(const bf16x8*)(Bs + swzoff(wn * 32 + 16 + lr, ka));
    acc00 = __builtin_amdgcn_mfma_f32_16x16x32_bf16(a0, b0, acc00, 0, 0, 0);
    acc01 = __builtin_amdgcn_mfma_f32_16x16x32_bf16(a0, b1, acc01, 0, 0, 0);
    acc10 = __builtin_amdgcn_mfma_f32_16x16x32_bf16(a1, b0, acc10, 0, 0, 0);
    acc11 = __builtin_amdgcn_mfma_f32_16x16x32_bf16(a1, b1, acc11, 0, 0, 0);
  }

  // C/D layout: col = lane&15, row = (lane>>4)*4 + reg  [measured m89]
  #pragma unroll
  for (int mt = 0; mt < 2; ++mt){
    f32x4 ac0 = mt ? acc10 : acc00;
    f32x4 ac1 = mt ? acc11 : acc01;
    #pragma unroll
    for (int r = 0; r < 4; ++r){
      int grow = rowbase + wm * 32 + mt * 16 + lg * 4 + r;
      if (grow < N_NODES){
        float dd = dis[grow];
        size_t base = (size_t)grow * HD + colbase + wn * 32 + lr;
        HN[base]      = f2b(ac0[r] * dd);
        HN[base + 16] = f2b(ac1[r] * dd);
      }
    }
  }
}

// ---------------- aggregation: OUTB[d] = bf16( dis[d]*(sum_{edges} HN[s] + HN[d]) ) ----------------
// 2 nodes per wave (32 lanes x 16B each), 4-deep edge unroll: up to 8 outstanding
// gathers per wave (agg is miss-latency / MLP-bound, R3 counters).

__global__ __launch_bounds__(256) void agg_k(const u16* __restrict__ HN, const int* __restrict__ rowptr,
                                             const int* __restrict__ colx, const float* __restrict__ dis,
                                             u16* __restrict__ OUTB)
{
  int wid = threadIdx.x >> 6, lane = threadIdx.x & 63;
  int node = blockIdx.x * 8 + wid * 2 + (lane >> 5);   // grid 12500*8 = 100000 exact
  int c0 = (lane & 31) * 8;                             // 8 cols (16B) per lane
  const u16* base = HN + (size_t)c0;

  f32x8 a0 = {0,0,0,0,0,0,0,0}, a1 = a0, a2 = a0, a3 = a0;
  int e = rowptr[node], end = rowptr[node + 1];
  for (; e + 4 <= end; e += 4){
    int s0 = colx[e], s1 = colx[e + 1], s2 = colx[e + 2], s3 = colx[e + 3];
    u16x8 v0 = *(const u16x8*)(base + (size_t)s0 * HD);
    u16x8 v1 = *(const u16x8*)(base + (size_t)s1 * HD);
    u16x8 v2 = *(const u16x8*)(base + (size_t)s2 * HD);
    u16x8 v3 = *(const u16x8*)(base + (size_t)s3 * HD);
    a0 += c8(v0); a1 += c8(v1); a2 += c8(v2); a3 += c8(v3);
  }
  for (; e < end; ++e)
    a0 += c8(*(const u16x8*)(base + (size_t)colx[e] * HD));
  a0 += c8(*(const u16x8*)(base + (size_t)node * HD));   // self-loop
  f32x8 res = ((a0 + a1) + (a2 + a3)) * dis[node];
  u16x8 o = { f2b(res[0]), f2b(res[1]), f2b(res[2]), f2b(res[3]),
              f2b(res[4]), f2b(res[5]), f2b(res[6]), f2b(res[7]) };
  *(u16x8*)(OUTB + (size_t)node * HD + c0) = o;
}

// ---------------- batch-norm over nodes ----------------

__global__ __launch_bounds__(256) void stat_k(const u16* __restrict__ OUTB, float* __restrict__ sums){
  int c = threadIdx.x;
  float s = 0.f, q = 0.f;
  for (int r = blockIdx.x; r < N_NODES; r += gridDim.x){
    float v = b2f(OUTB[(size_t)r * HD + c]);
    s += v; q += v * v;
  }
  atomicAdd(&sums[c], s);
  atomicAdd(&sums[HD + c], q);
}

__global__ __launch_bounds__(256) void prep_k(const float* __restrict__ sums, const float* __restrict__ gamma,
                                              const float* __restrict__ beta, float* __restrict__ prm){
  int c = threadIdx.x;
  float mean = sums[c] / (float)N_NODES;
  float var  = fmaxf(sums[HD + c] / (float)N_NODES - mean * mean, 0.f);
  float inv  = rsqrtf(var + BN_EPS);
  float a = gamma[c] * inv;
  prm[c] = a;
  prm[HD + c] = beta[c] - mean * a;
}

__global__ __launch_bounds__(256) void norm_k(const u16* __restrict__ OUTB, const float* __restrict__ prm,
                                              u16* __restrict__ XB){
  size_t i = (size_t)blockIdx.x * 256 + threadIdx.x;   // over N*HD/4
  int cq = (int)(i & 63);
  size_t base = i * 4;
  f32x4 v = c4(*(const u16x4*)(OUTB + base));
  f32x4 a = *(const f32x4*)(prm + cq * 4);
  f32x4 b = *(const f32x4*)(prm + HD + cq * 4);
  f32x4 y = v * a + b;
  u16x4 o = { f2b(fmaxf(y[0], 0.f)), f2b(fmaxf(y[1], 0.f)),
              f2b(fmaxf(y[2], 0.f)), f2b(fmaxf(y[3], 0.f)) };
  *(u16x4*)(XB + base) = o;
}

// ---------------- pooling + MLP head ----------------

// batch is SORTED: boundary-scan instead of 200k contended atomics.
__global__ __launch_bounds__(256) void bnd2_k(const int* __restrict__ batch, int* __restrict__ gs,
                                              int* __restrict__ ge){
  int i = blockIdx.x * 256 + threadIdx.x;
  if (i >= N_NODES) return;
  int b = batch[i];
  if (i == 0) gs[b] = 0;
  else {
    int p = batch[i - 1];
    if (p != b){ ge[p] = i; gs[b] = i; }
  }
  if (i == N_NODES - 1) ge[b] = N_NODES;
}

__global__ __launch_bounds__(256) void pool_k(const u16* __restrict__ xb, const int* __restrict__ gs,
                                              const int* __restrict__ ge, float* __restrict__ pooled){
  __shared__ float red[4][HD];
  int g = blockIdx.x;
  int s = gs[g], e = ge[g];
  int w = threadIdx.x >> 6;
  int c0 = (threadIdx.x & 63) * 4;
  f32x4 acc = {0,0,0,0};
  for (int r = s + w; r < e; r += 4){
    u16x4 v = *(const u16x4*)(xb + (size_t)r * HD + c0);
    acc += c4(v);
  }
  *(f32x4*)&red[w][c0] = acc;
  __syncthreads();
  if (w == 0){
    f32x4 t = *(f32x4*)&red[0][c0];
    t += *(f32x4*)&red[1][c0];
    t += *(f32x4*)&red[2][c0];
    t += *(f32x4*)&red[3][c0];
    float cntf = (e > s) ? (float)(e - s) : 1.0f;
    *(f32x4*)(pooled + g * HD + c0) = t * (1.0f / cntf);
  }
}

__global__ __launch_bounds__(256) void lin1_k(const float* __restrict__ pooled, const float* __restrict__ w,
                                              const float* __restrict__ b, float* __restrict__ z1){
  __shared__ float pr[HD];
  int g = blockIdx.x, c = threadIdx.x;
  pr[c] = pooled[g * HD + c];
  __syncthreads();
  float acc = b[c];
  #pragma unroll 8
  for (int k = 0; k < HD; ++k) acc = fmaf(pr[k], w[k * HD + c], acc);
  z1[g * HD + c] = acc;
}

__global__ __launch_bounds__(256) void bn1_k(float* __restrict__ z1, const float* __restrict__ g,
                                             const float* __restrict__ b){
  int c = threadIdx.x;
  float s = 0.f, q = 0.f;
  for (int r = 0; r < NGRAPH; ++r){
    float v = z1[r * HD + c];
    s += v; q += v * v;
  }
  float mean = s / (float)NGRAPH;
  float var  = fmaxf(q / (float)NGRAPH - mean * mean, 0.f);
  float inv  = rsqrtf(var + BN_EPS);
  float a = g[c] * inv, sh = b[c] - mean * a;
  for (int r = 0; r < NGRAPH; ++r)
    z1[r * HD + c] = fmaxf(z1[r * HD + c] * a + sh, 0.f);
}

__global__ __launch_bounds__(256) void lin2_k(const float* __restrict__ z1, const float* __restrict__ w,
                                              const float* __restrict__ b, float* __restrict__ out){
  __shared__ float zr[HD];
  int g = blockIdx.x;
  zr[threadIdx.x] = z1[g * HD + threadIdx.x];
  __syncthreads();
  if (threadIdx.x < NCLASS){
    float acc = b[threadIdx.x];
    #pragma unroll 8
    for (int k = 0; k < HD; ++k) acc = fmaf(zr[k], w[k * NCLASS + threadIdx.x], acc);
    out[g * NCLASS + threadIdx.x] = acc;
  }
}

// ---------------- host launch ----------------

extern "C" void kernel_launch(void* const* d_in, const int* in_sizes, int n_in,
                              void* d_out, int out_size, void* d_ws, size_t ws_size,
                              hipStream_t stream)
{
  const float* x      = (const float*)d_in[0];
  const int*   ei     = (const int*)d_in[1];
  const int*   batch  = (const int*)d_in[2];
  const float* W[3]   = {(const float*)d_in[3], (const float*)d_in[7], (const float*)d_in[11]};
  const float* gam[3] = {(const float*)d_in[5], (const float*)d_in[9], (const float*)d_in[13]};
  const float* bet[3] = {(const float*)d_in[6], (const float*)d_in[10], (const float*)d_in[14]};
  const float* lin1_w = (const float*)d_in[15];
  const float* lin1_b = (const float*)d_in[16];
  const float* bn1_g  = (const float*)d_in[17];
  const float* bn1_b  = (const float*)d_in[18];
  const float* lin2_w = (const float*)d_in[19];
  const float* lin2_b = (const float*)d_in[20];
  float* out = (float*)d_out;

  char* ws = (char*)d_ws;
  size_t off = 0;
  auto alloc = [&](size_t bytes) -> void* {
    void* p = ws + off;
    off = (off + bytes + 255) & ~(size_t)255;
    return p;
  };
  u16*   xb     = (u16*)alloc((size_t)N_NODES * HD * 2);
  u16*   hn     = (u16*)alloc((size_t)N_NODES * HD * 2);
  u16*   outb   = (u16*)alloc((size_t)N_NODES * HD * 2);
  u16*   wt     = (u16*)alloc((size_t)3 * HD * HD * 2);
  int*   cnt    = (int*)alloc((size_t)N_NODES * 4);
  int*   fill   = (int*)alloc((size_t)N_NODES * 4);
  int*   rowptr = (int*)alloc((size_t)(N_NODES + 1) * 4);
  int*   tmp    = (int*)alloc((size_t)N_NODES * 4);
  int*   bsum   = (int*)alloc(512 * 4);
  int*   boff   = (int*)alloc(512 * 4);
  int*   colx   = (int*)alloc((size_t)N_EDGES * 4);
  float* dis    = (float*)alloc((size_t)N_NODES * 4);
  float* bnsum  = (float*)alloc(2 * HD * 4);
  float* prm    = (float*)alloc(2 * HD * 4);
  int*   gs     = (int*)alloc(NGRAPH * 4);
  int*   ge     = (int*)alloc(NGRAPH * 4);
  float* pooled = (float*)alloc((size_t)NGRAPH * HD * 4);
  float* z1     = (float*)alloc((size_t)NGRAPH * HD * 4);
  (void)ws_size; (void)n_in; (void)in_sizes; (void)out_size;

  const int NB1 = (N_NODES + 255) / 256;            // 391

  hipMemsetAsync(cnt, 0, (size_t)N_NODES * 4, stream);
  hipMemsetAsync(fill, 0, (size_t)N_NODES * 4, stream);

  cvt_k<<<12500, 256, 0, stream>>>(x, xb);
  for (int l = 0; l < 3; ++l)
    wt_k<<<256, 256, 0, stream>>>(W[l], wt + (size_t)l * HD * HD);

  cnt_k<<<12500, 256, 0, stream>>>(ei, cnt);
  scan1_k<<<NB1, 256, 0, stream>>>(cnt, tmp, bsum);
  scan2_k<<<1, 512, 0, stream>>>(bsum, boff, NB1);
  scan3_k<<<(N_NODES + 256) / 256 + 1, 256, 0, stream>>>(tmp, boff, rowptr);
  fill_k<<<12500, 256, 0, stream>>>(ei, rowptr, fill, colx);
  dis_k<<<NB1, 256, 0, stream>>>(cnt, dis);

  for (int l = 0; l < 3; ++l){
    gemm_k<<<dim3(4, 1563), 256, 0, stream>>>(xb, wt + (size_t)l * HD * HD, dis, hn);
    agg_k<<<12500, 256, 0, stream>>>(hn, rowptr, colx, dis, outb);
    hipMemsetAsync(bnsum, 0, 2 * HD * 4, stream);
    stat_k<<<1024, 256, 0, stream>>>(outb, bnsum);
    prep_k<<<1, 256, 0, stream>>>(bnsum, gam[l], bet[l], prm);
    norm_k<<<25000, 256, 0, stream>>>(outb, prm, xb);
  }

  hipMemsetAsync(gs, 0x7f, NGRAPH * 4, stream);
  hipMemsetAsync(ge, 0, NGRAPH * 4, stream);
  bnd2_k<<<NB1, 256, 0, stream>>>(batch, gs, ge);
  pool_k<<<NGRAPH, 256, 0, stream>>>(xb, gs, ge, pooled);
  lin1_k<<<NGRAPH, 256, 0, stream>>>(pooled, lin1_w, lin1_b, z1);
  bn1_k<<<1, 256, 0, stream>>>(z1, bn1_g, bn1_b);
  lin2_k<<<NGRAPH, 256, 0, stream>>>(z1, lin2_w, lin2_b, out);
}